// Round 5
// baseline (667.921 us; speedup 1.0000x reference)
//
#include <hip/hip_runtime.h>

// WindowNonLocalDenoising on MI355X (gfx950) — Round 7.
// Decoupled phase-2: each wave OWNS one n'-tile end-to-end (TH -> aff ->
// softmax -> PV -> stores) with all intermediates in REGISTERS.
//   * Phase-2 barriers: 30 -> 0 (2 barriers/window total). No TT/ST/gsum LDS
//     buffers or their write traffic; no inter-wave convoy.
//   * Total MFMA per window unchanged (work redistributed, not duplicated).
//   * prep_kernel pre-quantizes theta/phi/proj to fp8 (x16) into d_ws once
//     per launch; all weight frags are direct 8B global loads (L2-hot),
//     deleting every per-window wfrag8 (loads+cvt) from the hot kernel.
//   * XT back to stride 264 (r5 layout): row bank-phase 2 dwords -> frag
//     reads spread banks; r6's stride-256+swizzle was ~8-way conflicted
//     (the +1.1e7 SQ_LDS_BANK_CONFLICT regression).
//   * In-register transposes (verified mappings):
//     TH:  D[e][n'] lane(q,l16) reg r = th[et*16+4q+r][l16]; pack -> pkT[et].
//       B-frag tfr[kk] lane(q,l16) byte b = th[32kk+8q+b][l16]
//       = lo:int from lane (q_s=2(q&1), l16) reg pkT[2kk+(q>>1)],
//         hi:int from lane (q_s=2(q&1)+1, l16) same reg.
//     p:   identical structure with mt <-> et, pm <-> pkT, km <-> kk.
//   * Row-sum of softmax is lane-local: per-lane partial over owned m's +
//     shfl_xor(16) + shfl_xor(32) (all q-lanes of a given n'=l16).
//   * No-max softmax retained from r6 (|logit| << 1 by weight scale; r6
//     passed with absmax 0.03125).
// LDS map: XT [225][264] @0 (59,400) | PT [225][144] @59,400 (32,400) |
//          Z [256][240] @91,800 (61,440). Total 153,240 <= 163,840.
// Reads of XT rows 225..239 / PT rows 225..239 (mt=14 tail) spill into the
// next region: garbage, but every consumer masks by index (pe=0, z=0, store
// gating), and NaN columns/rows are provably confined to dead outputs.

#define WS_   15
#define B_    4
#define C_    256
#define H_    200
#define H2    (H_*H_)
#define NHW   14
#define NWIN  (B_*NHW*NHW)   // 784
#define NPOS  225
#define NWAVE 16

#define XT_STRIDE 264
#define PT_STRIDE 144
#define Z_STRIDE  240

#define XT_OFF 0
#define PT_OFF 59400
#define Z_OFF  91800
#define LDS_BYTES 153240

// d_ws layout (fp8, value = fp8(w*16)):
#define THQ_OFF 0
#define PHQ_OFF 36864
#define PRQ_OFF 73728
#define WQ_BYTES 139264

typedef __attribute__((ext_vector_type(4))) float floatx4;

__device__ inline int pack4(float a, float b, float c, float d) {
    int pk = __builtin_amdgcn_cvt_pk_fp8_f32(a, b, 0, false);
    return __builtin_amdgcn_cvt_pk_fp8_f32(c, d, pk, true);
}
__device__ inline long ldsfrag(const char* p) { return *(const long*)p; }
__device__ inline long gfrag(const unsigned char* p) { return *(const long*)p; }

#define MFMA8(a,b,c) __builtin_amdgcn_mfma_f32_16x16x32_fp8_fp8((a),(b),(c),0,0,0)

// LDS-scoped barrier: orders this wave's LDS ops and syncs the block WITHOUT
// draining vmcnt. All inter-wave communication here is via LDS.
__device__ inline void bar_lds() {
    asm volatile("s_waitcnt lgkmcnt(0)" ::: "memory");
    __builtin_amdgcn_s_barrier();
}

// Pre-quantize weights to fp8 (x16 scale), bit-identical to the old wfrag8.
__global__ void prep_kernel(const float* __restrict__ tw,
                            const float* __restrict__ pw,
                            const float* __restrict__ prw,
                            unsigned char* __restrict__ wq)
{
    int idx = blockIdx.x * blockDim.x + threadIdx.x;
    for (int d = idx; d < WQ_BYTES / 4; d += gridDim.x * blockDim.x) {
        int base = d * 4;
        const float* src;
        int off;
        if (base < PHQ_OFF)      { src = tw;  off = base; }
        else if (base < PRQ_OFF) { src = pw;  off = base - PHQ_OFF; }
        else                     { src = prw; off = base - PRQ_OFF; }
        const float* p = src + off;
        ((int*)wq)[d] = pack4(p[0]*16.f, p[1]*16.f, p[2]*16.f, p[3]*16.f);
    }
}

__global__ __launch_bounds__(1024) void wnl_kernel(
    const float* __restrict__ x, const unsigned char* __restrict__ wq,
    float* __restrict__ out)
{
    __shared__ char lds[LDS_BYTES];
    char* XT = lds + XT_OFF;
    char* PT = lds + PT_OFF;
    char* Zs = lds + Z_OFF;

    const int tid  = threadIdx.x;
    const int wv   = tid >> 6;          // 0..15
    const int lane = tid & 63;
    const int q    = lane >> 4;
    const int l16  = lane & 15;

    const int wid  = blockIdx.x;
    const int b    = wid / (NHW*NHW);
    const int rr   = wid % (NHW*NHW);
    const int row0 = (rr / NHW) * WS_;
    const int col0 = (rr % NHW) * WS_;
    const float* xb = x + (size_t)b * C_ * H2;

    const unsigned char* thetaq = wq + THQ_OFF;
    const unsigned char* phiq   = wq + PHQ_OFF;
    const unsigned char* projq  = wq + PRQ_OFF;

    // ---- P1 weight frags: direct 8B loads from prep output (L2-hot).
    // Issued before the gather so latency hides under P0. ----
    long wAf[8], wBf[8];
    if (wv < 9) {
        const unsigned char* pa = phiq + (wv*16 + l16)*256 + q*8;
        const unsigned char* pb = projq + ((wv+7)*16 + l16)*256 + q*8;
        #pragma unroll
        for (int ck = 0; ck < 8; ++ck) { wAf[ck] = gfrag(pa + ck*32); wBf[ck] = gfrag(pb + ck*32); }
    } else {
        const unsigned char* pa = projq + ((wv-9)*16 + l16)*256 + q*8;
        #pragma unroll
        for (int ck = 0; ck < 8; ++ck) wAf[ck] = gfrag(pa + ck*32);
    }

    // ---- Phase 0: gather (reflect pad) -> XT fp8 [n][c], packed dwords.
    // thread <-> (n = tid&255, c0 = 4*(tid>>8)); 16 iters c = c0 + 16k.
    // Lanes = consecutive n -> coalesced ~60B spatial runs per c-plane.
    // Write banks: dword bank = (66n + col/4) mod 32 -> 2n phase: 16
    // consecutive lanes hit 16 distinct even banks (conflict-light). ----
    {
        const int gn  = tid & 255;
        const int gc0 = (tid >> 8) << 2;
        if (gn < NPOS) {
            int wr = row0 + gn / WS_;
            int wc = col0 + gn % WS_;
            int gr = (wr < H_) ? wr : (2*H_ - 2 - wr);
            int gc = (wc < H_) ? wc : (2*H_ - 2 - wc);
            const float* p = xb + (size_t)gc0 * H2 + (gr * H_ + gc);
            char* dst = XT + gn * XT_STRIDE;
            float a0 = p[0], a1 = p[H2], a2 = p[2*(size_t)H2], a3 = p[3*(size_t)H2];
            for (int k = 0; k < 16; ++k) {
                float b0=0.f, b1=0.f, b2=0.f, b3=0.f;
                if (k < 15) {   // issue next iter's loads before packing
                    const float* pn = p + (size_t)(16*(k+1)) * H2;
                    b0 = pn[0]; b1 = pn[H2]; b2 = pn[2*(size_t)H2]; b3 = pn[3*(size_t)H2];
                }
                *(int*)(dst + gc0 + 16*k) = pack4(a0, a1, a2, a3);
                a0=b0; a1=b1; a2=b2; a3=b3;
            }
        }
    }
    bar_lds();   // BAR 1: XT ready

    // ---- Phase 1: PT[m][e] (waves 0-8) + Z[o][m] (all waves), packed
    // dword writes via swapped-operand MFMA (r5/r6 verified). ----
    if (wv < 9) {
        for (int mt = 0; mt < 15; ++mt) {
            long xf[8];
            const char* xrow = XT + (mt*16 + l16) * XT_STRIDE + q*8;
            #pragma unroll
            for (int ck = 0; ck < 8; ++ck) xf[ck] = ldsfrag(xrow + ck*32);
            floatx4 accP = {0.f,0.f,0.f,0.f};
            floatx4 accZ = {0.f,0.f,0.f,0.f};
            #pragma unroll
            for (int ck = 0; ck < 8; ++ck) {
                accP = MFMA8(wAf[ck], xf[ck], accP);   // D[e][m]: e=4q+r, m=l16
                accZ = MFMA8(xf[ck], wBf[ck], accZ);   // D[m][o]: m=4q+r, o=l16
            }
            if (mt*16 + l16 < NPOS)   // PT has 225 rows; don't overflow into Z
                *(int*)(PT + (mt*16 + l16) * PT_STRIDE + wv*16 + 4*q) =
                    pack4(accP[0], accP[1], accP[2], accP[3]);
            float z[4];
            #pragma unroll
            for (int r = 0; r < 4; ++r) {
                int m = mt*16 + 4*q + r;
                z[r] = (m < NPOS) ? accZ[r] : 0.f;   // zero pad cols
            }
            *(int*)(Zs + ((wv+7)*16 + l16) * Z_STRIDE + mt*16 + 4*q) =
                pack4(z[0], z[1], z[2], z[3]);
        }
    } else {
        const int ot = wv - 9;
        for (int mt = 0; mt < 15; ++mt) {
            long xf[8];
            const char* xrow = XT + (mt*16 + l16) * XT_STRIDE + q*8;
            #pragma unroll
            for (int ck = 0; ck < 8; ++ck) xf[ck] = ldsfrag(xrow + ck*32);
            floatx4 accZ = {0.f,0.f,0.f,0.f};
            #pragma unroll
            for (int ck = 0; ck < 8; ++ck)
                accZ = MFMA8(xf[ck], wAf[ck], accZ);
            float z[4];
            #pragma unroll
            for (int r = 0; r < 4; ++r) {
                int m = mt*16 + 4*q + r;
                z[r] = (m < NPOS) ? accZ[r] : 0.f;
            }
            *(int*)(Zs + (ot*16 + l16) * Z_STRIDE + mt*16 + 4*q) =
                pack4(z[0], z[1], z[2], z[3]);
        }
    }
    bar_lds();   // BAR 2: PT + Z ready. No more barriers.

    // ---- Phase 2: wave wv (< 15) owns n'-tile nt = wv. All-register. ----
    if (wv < 15) {
        const int nt = wv;
        const int srcA = l16 + ((q & 1) << 5);   // lane of q_s = 2(q&1)
        const int srcB = srcA + 16;              // lane of q_s = 2(q&1)+1

        // xf: this wave's 16 XT rows as B-frags (rows nt*16+l16, all c).
        long xf[8];
        {
            const char* xrow = XT + (nt*16 + l16) * XT_STRIDE + q*8;
            #pragma unroll
            for (int ck = 0; ck < 8; ++ck) xf[ck] = ldsfrag(xrow + ck*32);
        }

        // (a) TH: 9 e-tiles; thw frags direct from global (L2-hot).
        int pkT[9];
        #pragma unroll
        for (int et = 0; et < 9; ++et) {
            const unsigned char* tp = thetaq + (et*16 + l16)*256 + q*8;
            long tf[8];
            #pragma unroll
            for (int ck = 0; ck < 8; ++ck) tf[ck] = gfrag(tp + ck*32);
            floatx4 acc = {0.f,0.f,0.f,0.f};
            #pragma unroll
            for (int ck = 0; ck < 8; ++ck)
                acc = MFMA8(tf[ck], xf[ck], acc);   // D[e][n']
            pkT[et] = pack4(acc[0], acc[1], acc[2], acc[3]);
        }
        // transpose pkT -> tfr (TH rows n' over e)
        long tfr[5];
        #pragma unroll
        for (int kk = 0; kk < 4; ++kk) {
            int a0 = __shfl(pkT[2*kk],   srcA);
            int a1 = __shfl(pkT[2*kk+1], srcA);
            int b0 = __shfl(pkT[2*kk],   srcB);
            int b1 = __shfl(pkT[2*kk+1], srcB);
            unsigned lo = (q >= 2) ? (unsigned)a1 : (unsigned)a0;
            unsigned hi = (q >= 2) ? (unsigned)b1 : (unsigned)b0;
            tfr[kk] = (long)lo | ((long)hi << 32);
        }
        {
            int a8 = __shfl(pkT[8], srcA);
            int b8 = __shfl(pkT[8], srcB);
            tfr[4] = (q < 2) ? ((long)(unsigned)a8 | ((long)(unsigned)b8 << 32)) : 0L;
        }

        // (b) aff + no-max softmax, all m-tiles; p packed to pm[].
        float ssum = 0.f;
        int pm[15];
        #pragma unroll
        for (int mt = 0; mt < 15; ++mt) {
            const char* prow = PT + (mt*16 + l16) * PT_STRIDE + q*8;
            floatx4 aacc = {0.f,0.f,0.f,0.f};
            #pragma unroll
            for (int kk = 0; kk < 4; ++kk)
                aacc = MFMA8(ldsfrag(prow + kk*32), tfr[kk], aacc);
            long p4 = (q < 2) ? ldsfrag(PT + (mt*16 + l16)*PT_STRIDE + 128 + q*8) : 0L;
            aacc = MFMA8(p4, tfr[4], aacc);
            float pe[4];
            #pragma unroll
            for (int r = 0; r < 4; ++r) {
                int m = mt*16 + 4*q + r;
                // aff' = 256*aff_true -> logits scale 1/(12*256); masked pad -> 0
                pe[r] = (m < NPOS) ? __expf(aacc[r] * (1.0f/3072.0f)) : 0.f;
                ssum += pe[r];
            }
            pm[mt] = pack4(pe[0], pe[1], pe[2], pe[3]);
        }
        ssum += __shfl_xor(ssum, 16);
        ssum += __shfl_xor(ssum, 32);
        const float sinv = __builtin_amdgcn_rcpf(16.0f * ssum);

        // transpose pm -> sfr (p rows n' over m), same mapping as tfr
        long sfr[8];
        #pragma unroll
        for (int km = 0; km < 7; ++km) {
            int a0 = __shfl(pm[2*km],   srcA);
            int a1 = __shfl(pm[2*km+1], srcA);
            int b0 = __shfl(pm[2*km],   srcB);
            int b1 = __shfl(pm[2*km+1], srcB);
            unsigned lo = (q >= 2) ? (unsigned)a1 : (unsigned)a0;
            unsigned hi = (q >= 2) ? (unsigned)b1 : (unsigned)b0;
            sfr[km] = (long)lo | ((long)hi << 32);
        }
        {
            int a8 = __shfl(pm[14], srcA);
            int b8 = __shfl(pm[14], srcB);
            // q==0: m 224..231 (225+ are fp8(0) from the pe mask). q>=1: the
            // matching Z bytes are zeros, frag content irrelevant -> 0.
            sfr[7] = (q == 0) ? ((long)(unsigned)a8 | ((long)(unsigned)b8 << 32)) : 0L;
        }

        // (c) PV: D[o][n'] for all 16 o-tiles; residual x prefetched 1 tile
        // ahead; NT stores (write-once stream).
        const int n_o  = nt*16 + l16;
        const int wr_o = row0 + n_o / WS_;
        const int wc_o = col0 + n_o % WS_;
        const bool valid = (n_o < NPOS) && (wr_o < H_) && (wc_o < H_);
        const size_t gb0 = (size_t)b * C_ * H2 + ((size_t)wr_o * H_ + wc_o);
        float xr0=0.f, xr1=0.f, xr2=0.f, xr3=0.f;
        if (valid) {
            const float* p = x + gb0 + (size_t)(4*q) * H2;
            xr0 = p[0]; xr1 = p[H2]; xr2 = p[2*(size_t)H2]; xr3 = p[3*(size_t)H2];
        }
        #pragma unroll
        for (int ot = 0; ot < 16; ++ot) {
            float nx0=0.f, nx1=0.f, nx2=0.f, nx3=0.f;
            if (ot < 15 && valid) {   // prefetch residuals for ot+1
                const float* p = x + gb0 + (size_t)((ot+1)*16 + 4*q) * H2;
                nx0 = p[0]; nx1 = p[H2]; nx2 = p[2*(size_t)H2]; nx3 = p[3*(size_t)H2];
            }
            const char* zrow = Zs + (ot*16 + l16) * Z_STRIDE + q*8;
            floatx4 acc = {0.f,0.f,0.f,0.f};
            #pragma unroll
            for (int km = 0; km < 7; ++km)
                acc = MFMA8(ldsfrag(zrow + km*32), sfr[km], acc);
            long z7 = (q < 2) ? ldsfrag(Zs + (ot*16 + l16)*Z_STRIDE + 224 + q*8) : 0L;
            acc = MFMA8(z7, sfr[7], acc);
            if (valid) {
                float* o0 = out + gb0 + (size_t)(ot*16 + 4*q) * H2;
                __builtin_nontemporal_store(xr0 + acc[0]*sinv, o0);
                __builtin_nontemporal_store(xr1 + acc[1]*sinv, o0 + H2);
                __builtin_nontemporal_store(xr2 + acc[2]*sinv, o0 + 2*(size_t)H2);
                __builtin_nontemporal_store(xr3 + acc[3]*sinv, o0 + 3*(size_t)H2);
            }
            xr0=nx0; xr1=nx1; xr2=nx2; xr3=nx3;
        }
    }
}

extern "C" void kernel_launch(void* const* d_in, const int* in_sizes, int n_in,
                              void* d_out, int out_size, void* d_ws, size_t ws_size,
                              hipStream_t stream) {
    (void)in_sizes; (void)n_in; (void)out_size; (void)ws_size;
    const float* x   = (const float*)d_in[0];
    const float* tw  = (const float*)d_in[1];
    const float* pw  = (const float*)d_in[2];
    const float* prw = (const float*)d_in[3];
    unsigned char* wqd = (unsigned char*)d_ws;
    prep_kernel<<<64, 256, 0, stream>>>(tw, pw, prw, wqd);
    wnl_kernel<<<NWIN, 1024, 0, stream>>>(x, wqd, (float*)d_out);
}